// Round 18
// baseline (433.622 us; speedup 1.0000x reference)
//
#include <hip/hip_runtime.h>
#include <hip/hip_bf16.h>

// B=2,S=2048 -> T=4096 tokens, D=1024, H=2048, E=8, top_k=2
#define TOK 4096
#define DD 1024
#define HH 2048
#define NE 8
#define RTOT (TOK * 2)

typedef __attribute__((ext_vector_type(8))) short bf16x8;
typedef __attribute__((ext_vector_type(4))) float f32x4;

static __device__ __forceinline__ unsigned short f2bf(float f) {
  union { float f; unsigned int u; } v; v.f = f;
  unsigned int r = v.u + 0x7fffu + ((v.u >> 16) & 1u);
  return (unsigned short)(r >> 16);
}

// async global->LDS, 16B/lane; LDS dest = wave-uniform base + lane*16
static __device__ __forceinline__ void gload16(const unsigned short* g, unsigned short* l) {
  __builtin_amdgcn_global_load_lds(
      (const __attribute__((address_space(1))) unsigned int*)g,
      (__attribute__((address_space(3))) unsigned int*)l, 16, 0, 0);
}

// packed f32x2 -> bf16x2 (RNE), single HW instruction
#define CVT(d, lo, hi) asm("v_cvt_pk_bf16_f32 %0, %1, %2" : "=v"(d) : "v"(lo), "v"(hi))

#define BARX() do { asm volatile("" ::: "memory"); __builtin_amdgcn_s_barrier(); asm volatile("" ::: "memory"); } while (0)
#define VMCNT(n) asm volatile("s_waitcnt vmcnt(" #n ")" ::: "memory")

// ---------------- router: fp32 scores, top-2 softmax; emits Xb (bf16 x) ----------------
__global__ void router_k(const float* __restrict__ x, const float* __restrict__ gw,
                         unsigned short* __restrict__ xb,
                         int* __restrict__ topi, float* __restrict__ topp,
                         int* __restrict__ counts) {
  const int lane = threadIdx.x & 63;
  const int t = blockIdx.x * 4 + (threadIdx.x >> 6);
  const float4* xr = (const float4*)(x + (size_t)t * DD);
  unsigned int* xw = (unsigned int*)(xb + (size_t)t * DD);
  float acc[NE];
#pragma unroll
  for (int e = 0; e < NE; ++e) acc[e] = 0.f;
#pragma unroll
  for (int i = 0; i < 4; ++i) {
    const float4 xv = xr[i * 64 + lane];
    unsigned int p0, p1;
    CVT(p0, xv.x, xv.y);
    CVT(p1, xv.z, xv.w);
    xw[(i * 64 + lane) * 2] = p0;
    xw[(i * 64 + lane) * 2 + 1] = p1;
#pragma unroll
    for (int e = 0; e < NE; ++e) {
      const float4 gv = ((const float4*)(gw + (size_t)e * DD))[i * 64 + lane];
      acc[e] += xv.x * gv.x + xv.y * gv.y + xv.z * gv.z + xv.w * gv.w;
    }
  }
#pragma unroll
  for (int e = 0; e < NE; ++e)
#pragma unroll
    for (int s = 32; s > 0; s >>= 1) acc[e] += __shfl_xor(acc[e], s, 64);
  if (lane == 0) {
    int i0 = 0; float v0 = acc[0];
#pragma unroll
    for (int e = 1; e < NE; ++e) if (acc[e] > v0) { v0 = acc[e]; i0 = e; }
    int i1 = -1; float v1 = -1e30f;
#pragma unroll
    for (int e = 0; e < NE; ++e) if (e != i0 && acc[e] > v1) { v1 = acc[e]; i1 = e; }
    const float ex = __expf(v1 - v0);
    const float inv = 1.f / (1.f + ex);
    topi[t * 2] = i0; topi[t * 2 + 1] = i1;
    topp[t * 2] = inv; topp[t * 2 + 1] = ex * inv;
    atomicAdd(&counts[i0], 1); atomicAdd(&counts[i1], 1);
  }
}

// ---------------- deterministic sorted compaction (ballot prefix-scan) ----------------
__global__ __launch_bounds__(256) void compact_k(
    const int* __restrict__ topi, const float* __restrict__ topp,
    const int* __restrict__ counts, int* __restrict__ perm, float* __restrict__ prow) {
  const int e = blockIdx.x;
  const int tid = threadIdx.x, lane = tid & 63, wv = tid >> 6;
  __shared__ int wsum[4];
  __shared__ int cbase;
  if (tid == 0) {
    int b = 0;
    for (int i = 0; i < e; ++i) b += counts[i];
    cbase = b;
  }
  __syncthreads();
  for (int c0 = 0; c0 < TOK; c0 += 256) {
    const int t = c0 + tid;
    const int a = topi[2 * t], b = topi[2 * t + 1];
    const int k = (a == e) ? 0 : ((b == e) ? 1 : -1);
    const unsigned long long bal = __ballot(k >= 0);
    const int rank = __popcll(bal & ((1ull << lane) - 1ull));
    if (lane == 0) wsum[wv] = __popcll(bal);
    __syncthreads();
    int woff = 0;
#pragma unroll
    for (int i = 0; i < 4; ++i) if (i < wv) woff += wsum[i];
    const int ctot = wsum[0] + wsum[1] + wsum[2] + wsum[3];
    if (k >= 0) {
      const int pos = cbase + woff + rank;
      perm[pos] = t;
      prow[pos] = topp[2 * t + k];
    }
    __syncthreads();
    if (tid == 0) cbase += ctot;
    __syncthreads();
  }
}

// ================= GEMM1: weights-stationary =================
// Block = (e, 32 h-cols). Loads w1/w2 panel fp32->bf16 ONCE into 128KB LDS
// ([64 rows: 16G|16U|16G|16U][K=1024], chunk^(row&7) swizzle), then loops all
// M-tiles (BM=128) with counted-vmcnt A pipeline. LDS = 128K(B) + 32K(A dbuf) = 160KB.
__global__ __launch_bounds__(256) void gemm1_k(
    const unsigned short* __restrict__ Xb, const float* __restrict__ w1,
    const float* __restrict__ w2, const int* __restrict__ counts,
    const int* __restrict__ perm, unsigned short* __restrict__ hbuf) {
  const int e = blockIdx.x >> 6;
  const int jb = (blockIdx.x & 63) * 32;
  int off = 0;
  for (int i = 0; i < e; ++i) off += counts[i];
  const int ne = counts[e];

  extern __shared__ __align__(16) unsigned short lds[];
  // B: [0, 65536) shorts ; A buf b: 65536 + b*8192

  const int tid = threadIdx.x, lane = tid & 63, wv = tid >> 6;

  // ---- one-time weight panel load: 2 mats x 32 k-rows/iter x 32 cols ----
  {
    const int kr = tid >> 3, jc = (tid & 7) * 4;   // k-row-in-32, col base
#pragma unroll
    for (int m = 0; m < 2; ++m) {
      const float* wsrc = (m ? w2 : w1) + (size_t)e * DD * HH + jb + jc;
      for (int p = 0; p < 4; ++p) {
        float4 v0_, v1_, v2_, v3_, v4_, v5_, v6_, v7_;
        const float* bp = wsrc + (size_t)(p * 256 + kr) * HH;
        v0_ = *(const float4*)(bp);
        v1_ = *(const float4*)(bp + (size_t)32 * HH);
        v2_ = *(const float4*)(bp + (size_t)64 * HH);
        v3_ = *(const float4*)(bp + (size_t)96 * HH);
        v4_ = *(const float4*)(bp + (size_t)128 * HH);
        v5_ = *(const float4*)(bp + (size_t)160 * HH);
        v6_ = *(const float4*)(bp + (size_t)192 * HH);
        v7_ = *(const float4*)(bp + (size_t)224 * HH);
#define WSTORE(V, S)                                                      \
        do {                                                              \
          const int k = p * 256 + (S) * 32 + kr;                          \
          unsigned int d0, d1;                                            \
          CVT(d0, V.x, V.y);                                              \
          CVT(d1, V.z, V.w);                                              \
          _Pragma("unroll")                                               \
          for (int c = 0; c < 4; ++c) {                                   \
            const int j = jc + c;                                         \
            const int grow = ((j >> 4) << 5) + (j & 15) + m * 16;         \
            const unsigned int dv = (c < 2) ? d0 : d1;                    \
            const unsigned short hv =                                     \
                (c & 1) ? (unsigned short)(dv >> 16) : (unsigned short)dv; \
            lds[grow * 1024 + (((k >> 3) ^ (grow & 7)) << 3) + (k & 7)] = hv; \
          }                                                               \
        } while (0)
        WSTORE(v0_, 0); WSTORE(v1_, 1); WSTORE(v2_, 2); WSTORE(v3_, 3);
        WSTORE(v4_, 4); WSTORE(v5_, 5); WSTORE(v6_, 6); WSTORE(v7_, 7);
#undef WSTORE
      }
    }
  }
  __syncthreads();

  const int srow = lane >> 3;
  const int schunk = ((lane & 7) ^ srow) * 8;
  const int wr = wv >> 1, wc = wv & 1;
  const int lr = lane & 15, kc = lane >> 4;

#define A_ISSUE(b)                                                        \
  do {                                                                    \
    _Pragma("unroll")                                                     \
    for (int q = 0; q < 4; ++q) {                                         \
      gload16(pA[q], lds + 65536 + (b) * 8192 + (wv * 32 + q * 8) * 64);  \
      pA[q] += 64;                                                        \
    }                                                                     \
  } while (0)

#define G1_COMPUTE(b, kt)                                                 \
  do {                                                                    \
    const unsigned short* Ab = lds + 65536 + (b) * 8192;                  \
    _Pragma("unroll")                                                     \
    for (int kk = 0; kk < 2; ++kk) {                                      \
      bf16x8 af[4], bg, bu;                                               \
      _Pragma("unroll")                                                   \
      for (int mf = 0; mf < 4; ++mf)                                      \
        af[mf] = *(const bf16x8*)&Ab[(wr * 64 + mf * 16 + lr) * 64 +      \
                                     ((kk * 4 + kc) ^ (lr & 7)) * 8];     \
      {                                                                   \
        const int rg = wc * 32 + lr;                                      \
        bg = *(const bf16x8*)&lds[rg * 1024 +                             \
              (((kt) * 8 + kk * 4 + kc) ^ (rg & 7)) * 8];                 \
        const int ru = wc * 32 + 16 + lr;                                 \
        bu = *(const bf16x8*)&lds[ru * 1024 +                             \
              (((kt) * 8 + kk * 4 + kc) ^ (ru & 7)) * 8];                 \
      }                                                                   \
      _Pragma("unroll")                                                   \
      for (int mf = 0; mf < 4; ++mf) {                                    \
        acc[mf][0] = __builtin_amdgcn_mfma_f32_16x16x32_bf16(             \
            af[mf], bg, acc[mf][0], 0, 0, 0);                             \
        acc[mf][1] = __builtin_amdgcn_mfma_f32_16x16x32_bf16(             \
            af[mf], bu, acc[mf][1], 0, 0, 0);                             \
      }                                                                   \
    }                                                                     \
  } while (0)

  for (int m0 = 0; m0 < ne; m0 += 128) {
    const unsigned short* pA[4];
#pragma unroll
    for (int q = 0; q < 4; ++q) {
      const int row = wv * 32 + q * 8 + srow;
      pA[q] = Xb + (size_t)perm[off + min(m0 + row, ne - 1)] * DD + schunk;
    }

    f32x4 acc[4][2];
#pragma unroll
    for (int a = 0; a < 4; ++a) {
      acc[a][0] = f32x4{0.f, 0.f, 0.f, 0.f};
      acc[a][1] = f32x4{0.f, 0.f, 0.f, 0.f};
    }

    BARX();                        // prior M-tile compute done before restaging
    A_ISSUE(0);
    A_ISSUE(1);
    VMCNT(4); BARX();
    for (int t = 0; t < 16; ++t) {
      const int cur = t & 1;
      G1_COMPUTE(cur, t);
      if (t == 15) break;
      BARX();
      if (t < 14) { A_ISSUE(cur); VMCNT(4); }
      else VMCNT(0);
      BARX();
    }

    // epilogue: silu(G)*U -> hbuf cols jb + wc*16 + lr
#pragma unroll
    for (int mf = 0; mf < 4; ++mf) {
      const f32x4 g = acc[mf][0], u = acc[mf][1];
      const int hcol = jb + wc * 16 + lr;
#pragma unroll
      for (int r = 0; r < 4; ++r) {
        const int rl = m0 + wr * 64 + mf * 16 + kc * 4 + r;
        if (rl < ne) {
          const float gg = g[r], uu = u[r];
          const float hv = gg / (1.f + __expf(-gg)) * uu;
          hbuf[(size_t)(off + rl) * HH + hcol] = f2bf(hv);
        }
      }
    }
  }
#undef A_ISSUE
#undef G1_COMPUTE
}

// ================= GEMM2: weights-stationary =================
// Block = (e, 32 d-cols). w3 panel fp32->bf16 once into 128KB LDS
// ([32 rows][K=2048], swizzled). M-loop over h rows; atomicAdd epilogue.
__global__ __launch_bounds__(256) void gemm2_k(
    const unsigned short* __restrict__ hbuf, const float* __restrict__ w3,
    const int* __restrict__ counts, const int* __restrict__ perm,
    const float* __restrict__ prow, float* __restrict__ out) {
  const int e = blockIdx.x >> 5;
  const int n1 = (blockIdx.x & 31) * 32;
  int off = 0;
  for (int i = 0; i < e; ++i) off += counts[i];
  const int ne = counts[e];

  extern __shared__ __align__(16) unsigned short lds[];
  // B: [0, 65536) shorts (32 rows x 2048) ; A buf b: 65536 + b*8192

  const int tid = threadIdx.x, lane = tid & 63, wv = tid >> 6;

  // ---- one-time w3 panel load: 32 k-rows/iter x 32 cols, 64 iters (8x8) ----
  {
    const int kr = tid >> 3, jc = (tid & 7) * 4;
    const float* wsrc = w3 + (size_t)e * HH * DD + n1 + jc;
    for (int p = 0; p < 8; ++p) {
      float4 v0_, v1_, v2_, v3_, v4_, v5_, v6_, v7_;
      const float* bp = wsrc + (size_t)(p * 256 + kr) * DD;
      v0_ = *(const float4*)(bp);
      v1_ = *(const float4*)(bp + (size_t)32 * DD);
      v2_ = *(const float4*)(bp + (size_t)64 * DD);
      v3_ = *(const float4*)(bp + (size_t)96 * DD);
      v4_ = *(const float4*)(bp + (size_t)128 * DD);
      v5_ = *(const float4*)(bp + (size_t)160 * DD);
      v6_ = *(const float4*)(bp + (size_t)192 * DD);
      v7_ = *(const float4*)(bp + (size_t)224 * DD);
#define WSTORE(V, S)                                                      \
      do {                                                                \
        const int k = p * 256 + (S) * 32 + kr;                            \
        unsigned int d0, d1;                                              \
        CVT(d0, V.x, V.y);                                                \
        CVT(d1, V.z, V.w);                                                \
        _Pragma("unroll")                                                 \
        for (int c = 0; c < 4; ++c) {                                     \
          const int row = jc + c;                                         \
          const unsigned int dv = (c < 2) ? d0 : d1;                      \
          const unsigned short hv =                                       \
              (c & 1) ? (unsigned short)(dv >> 16) : (unsigned short)dv;  \
          lds[row * 2048 + (((k >> 3) ^ (row & 7)) << 3) + (k & 7)] = hv; \
        }                                                                 \
      } while (0)
      WSTORE(v0_, 0); WSTORE(v1_, 1); WSTORE(v2_, 2); WSTORE(v3_, 3);
      WSTORE(v4_, 4); WSTORE(v5_, 5); WSTORE(v6_, 6); WSTORE(v7_, 7);
#undef WSTORE
    }
  }
  __syncthreads();

  const int srow = lane >> 3;
  const int schunk = ((lane & 7) ^ srow) * 8;
  const int wr = wv >> 1, wc = wv & 1;
  const int lr = lane & 15, kc = lane >> 4;

#define A_ISSUE(b)                                                        \
  do {                                                                    \
    _Pragma("unroll")                                                     \
    for (int q = 0; q < 4; ++q) {                                         \
      gload16(pA[q], lds + 65536 + (b) * 8192 + (wv * 32 + q * 8) * 64);  \
      pA[q] += 64;                                                        \
    }                                                                     \
  } while (0)

#define G2_COMPUTE(b, kt)                                                 \
  do {                                                                    \
    const unsigned short* Ab = lds + 65536 + (b) * 8192;                  \
    _Pragma("unroll")                                                     \
    for (int kk = 0; kk < 2; ++kk) {                                      \
      bf16x8 af[4], bf;                                                   \
      _Pragma("unroll")                                                   \
      for (int mf = 0; mf < 4; ++mf)                                      \
        af[mf] = *(const bf16x8*)&Ab[(wr * 64 + mf * 16 + lr) * 64 +      \
                                     ((kk * 4 + kc) ^ (lr & 7)) * 8];     \
      {                                                                   \
        const int row = wc * 16 + lr;                                     \
        bf = *(const bf16x8*)&lds[row * 2048 +                            \
              (((kt) * 8 + kk * 4 + kc) ^ (row & 7)) * 8];                \
      }                                                                   \
      _Pragma("unroll")                                                   \
      for (int mf = 0; mf < 4; ++mf)                                      \
        acc[mf] = __builtin_amdgcn_mfma_f32_16x16x32_bf16(                \
            af[mf], bf, acc[mf], 0, 0, 0);                                \
    }                                                                     \
  } while (0)

  for (int m0 = 0; m0 < ne; m0 += 128) {
    const unsigned short* pA[4];
#pragma unroll
    for (int q = 0; q < 4; ++q) {
      const int row = wv * 32 + q * 8 + srow;
      pA[q] = hbuf + (size_t)(off + min(m0 + row, ne - 1)) * HH + schunk;
    }

    f32x4 acc[4];
#pragma unroll
    for (int a = 0; a < 4; ++a) acc[a] = f32x4{0.f, 0.f, 0.f, 0.f};

    BARX();
    A_ISSUE(0);
    A_ISSUE(1);
    VMCNT(4); BARX();
    for (int t = 0; t < 32; ++t) {
      const int cur = t & 1;
      G2_COMPUTE(cur, t);
      if (t == 31) break;
      BARX();
      if (t < 30) { A_ISSUE(cur); VMCNT(4); }
      else VMCNT(0);
      BARX();
    }

    // epilogue: out[tok][n1 + wc*16 + lr] += prob * acc
#pragma unroll
    for (int mf = 0; mf < 4; ++mf)
#pragma unroll
      for (int r = 0; r < 4; ++r) {
        const int rl = m0 + wr * 64 + mf * 16 + kc * 4 + r;
        if (rl < ne) {
          const int tok = perm[off + rl];
          const float p = prow[off + rl];
          atomicAdd(out + (size_t)tok * DD + n1 + wc * 16 + lr, p * acc[mf][r]);
        }
      }
  }
#undef A_ISSUE
#undef G2_COMPUTE
}

// ---------------- workspace layout ----------------
#define WS_COUNTS 0
#define WS_TOPI 128
#define WS_TOPP (WS_TOPI + TOK * 2 * 4)
#define WS_PERM (WS_TOPP + TOK * 2 * 4)
#define WS_PROW (WS_PERM + RTOT * 4)
#define WS_XB ((WS_PROW + RTOT * 4 + 255) & ~(size_t)255)
#define WS_H (WS_XB + (size_t)TOK * DD * 2)
// end = WS_H + RTOT*HH*2 ~= 41.5 MB

extern "C" void kernel_launch(void* const* d_in, const int* in_sizes, int n_in,
                              void* d_out, int out_size, void* d_ws, size_t ws_size,
                              hipStream_t stream) {
  const float* x = (const float*)d_in[0];
  const float* gw = (const float*)d_in[1];
  const float* w1 = (const float*)d_in[2];
  const float* w2 = (const float*)d_in[3];
  const float* w3 = (const float*)d_in[4];
  float* out = (float*)d_out;
  char* ws = (char*)d_ws;

  int* counts = (int*)(ws + WS_COUNTS);
  int* topi = (int*)(ws + WS_TOPI);
  float* topp = (float*)(ws + WS_TOPP);
  int* perm = (int*)(ws + WS_PERM);
  float* prow = (float*)(ws + WS_PROW);
  unsigned short* Xb = (unsigned short*)(ws + WS_XB);
  unsigned short* hbuf = (unsigned short*)(ws + WS_H);

  hipFuncSetAttribute((const void*)gemm1_k, hipFuncAttributeMaxDynamicSharedMemorySize, 163840);
  hipFuncSetAttribute((const void*)gemm2_k, hipFuncAttributeMaxDynamicSharedMemorySize, 163840);

  hipMemsetAsync(ws, 0, 128, stream);
  hipMemsetAsync(out, 0, (size_t)out_size * sizeof(float), stream);
  router_k<<<TOK / 4, 256, 0, stream>>>(x, gw, Xb, topi, topp, counts);
  compact_k<<<NE, 256, 0, stream>>>(topi, topp, counts, perm, prow);
  // weights-stationary: 8 experts x 64 h-panels / x 32 d-panels
  gemm1_k<<<NE * 64, 256, 163840, stream>>>(Xb, w1, w2, counts, perm, hbuf);
  gemm2_k<<<NE * 32, 256, 163840, stream>>>(hbuf, w3, counts, perm, prow, out);
}

// Round 19
// 339.844 us; speedup vs baseline: 1.2759x; 1.2759x over previous
//
#include <hip/hip_runtime.h>
#include <hip/hip_bf16.h>

// B=2,S=2048 -> T=4096 tokens, D=1024, H=2048, E=8, top_k=2
#define TOK 4096
#define DD 1024
#define HH 2048
#define NE 8
#define RTOT (TOK * 2)
#define MAXT1 72   // max Sum ceil(ne/128) = 64 + 7 (+1 pad)
#define G1TILES (MAXT1 * 32)   // 2304 gemm1 blocks; then 4096 w3-transpose tail blocks

typedef __attribute__((ext_vector_type(8))) short bf16x8;
typedef __attribute__((ext_vector_type(4))) float f32x4;

static __device__ __forceinline__ unsigned short f2bf(float f) {
  union { float f; unsigned int u; } v; v.f = f;
  unsigned int r = v.u + 0x7fffu + ((v.u >> 16) & 1u);
  return (unsigned short)(r >> 16);
}

// async global->LDS, 16B/lane; LDS dest = wave-uniform base + lane*16
static __device__ __forceinline__ void gload16(const unsigned short* g, unsigned short* l) {
  __builtin_amdgcn_global_load_lds(
      (const __attribute__((address_space(1))) unsigned int*)g,
      (__attribute__((address_space(3))) unsigned int*)l, 16, 0, 0);
}

// packed f32x2 -> bf16x2 (RNE), single HW instruction
#define CVT(d, lo, hi) asm("v_cvt_pk_bf16_f32 %0, %1, %2" : "=v"(d) : "v"(lo), "v"(hi))

#define BARX() do { asm volatile("" ::: "memory"); __builtin_amdgcn_s_barrier(); asm volatile("" ::: "memory"); } while (0)
#define VMCNT8() asm volatile("s_waitcnt vmcnt(8)" ::: "memory")
#define VMCNT0() asm volatile("s_waitcnt vmcnt(0)" ::: "memory")

// ---------------- pre-kernel: router (blocks 0..1023) + w1/w2 transpose (1024..9215) ----
// (w3's transpose is moved into gemm1_k's tail blocks -> hidden under gemm1 compute.)
__global__ __launch_bounds__(256) void pre_k(
    const float* __restrict__ x, const float* __restrict__ gw,
    unsigned short* __restrict__ xb, int* __restrict__ topi, float* __restrict__ topp,
    int* __restrict__ counts,
    const float* __restrict__ w1, const float* __restrict__ w2,
    unsigned short* __restrict__ wgu) {
  __shared__ unsigned short tbuf[64 * 72];
  const int tid = threadIdx.x;
  const int lane = tid & 63, wv = tid >> 6;

  if (blockIdx.x < 1024) {
    // ---- router ----
    const int t = blockIdx.x * 4 + wv;
    const float4* xr = (const float4*)(x + (size_t)t * DD);
    unsigned int* xw = (unsigned int*)(xb + (size_t)t * DD);
    float acc[NE];
#pragma unroll
    for (int e = 0; e < NE; ++e) acc[e] = 0.f;
#pragma unroll
    for (int i = 0; i < 4; ++i) {
      const float4 xv = xr[i * 64 + lane];
      unsigned int p0, p1;
      CVT(p0, xv.x, xv.y);
      CVT(p1, xv.z, xv.w);
      xw[(i * 64 + lane) * 2] = p0;
      xw[(i * 64 + lane) * 2 + 1] = p1;
#pragma unroll
      for (int e = 0; e < NE; ++e) {
        const float4 gv = ((const float4*)(gw + (size_t)e * DD))[i * 64 + lane];
        acc[e] += xv.x * gv.x + xv.y * gv.y + xv.z * gv.z + xv.w * gv.w;
      }
    }
#pragma unroll
    for (int e = 0; e < NE; ++e)
#pragma unroll
      for (int s = 32; s > 0; s >>= 1) acc[e] += __shfl_xor(acc[e], s, 64);
    if (lane == 0) {
      int i0 = 0; float v0 = acc[0];
#pragma unroll
      for (int e = 1; e < NE; ++e) if (acc[e] > v0) { v0 = acc[e]; i0 = e; }
      int i1 = -1; float v1 = -1e30f;
#pragma unroll
      for (int e = 0; e < NE; ++e) if (e != i0 && acc[e] > v1) { v1 = acc[e]; i1 = e; }
      const float ex = __expf(v1 - v0);
      const float inv = 1.f / (1.f + ex);
      topi[t * 2] = i0; topi[t * 2 + 1] = i1;
      topp[t * 2] = inv; topp[t * 2 + 1] = ex * inv;
      atomicAdd(&counts[i0], 1); atomicAdd(&counts[i1], 1);
    }
    return;
  }

  // ---- w1/w2 transpose (R11 code): 64x64 tile -> wgu interleaved G/U rows ----
  const int bid = blockIdx.x - 1024;
  const int z = bid >> 9;               // 0..15
  const int xt = bid & 511;
  const int mat = z >> 3, e = z & 7;
  const float* in = (mat ? w2 : w1) + (size_t)e * DD * HH;
  const int tc = xt & 31, tr = xt >> 5;
  const int c0 = tc * 64, r0 = tr * 64;
#pragma unroll
  for (int p = 0; p < 4; ++p) {
    const int rb = (wv * 4 + p) * 4;
    ushort4 o;
    o.x = f2bf(in[(size_t)(r0 + rb + 0) * HH + c0 + lane]);
    o.y = f2bf(in[(size_t)(r0 + rb + 1) * HH + c0 + lane]);
    o.z = f2bf(in[(size_t)(r0 + rb + 2) * HH + c0 + lane]);
    o.w = f2bf(in[(size_t)(r0 + rb + 3) * HH + c0 + lane]);
    *(ushort4*)&tbuf[lane * 72 + rb] = o;
  }
  __syncthreads();
#pragma unroll
  for (int q = 0; q < 2; ++q) {
    const int idx = q * 256 + tid;
    const int crow = idx >> 3, seg = idx & 7;
    const int j = c0 + crow;
    const int R = ((j >> 4) << 5) + (j & 15) + mat * 16;
    *(uint4*)&wgu[((size_t)e * 2 * HH + R) * DD + r0 + seg * 8] =
        *(const uint4*)&tbuf[crow * 72 + seg * 8];
  }
}

// ---------------- deterministic sorted compaction (ballot prefix-scan) ----------------
__global__ __launch_bounds__(256) void compact_k(
    const int* __restrict__ topi, const float* __restrict__ topp,
    const int* __restrict__ counts, int* __restrict__ perm, float* __restrict__ prow) {
  const int e = blockIdx.x;
  const int tid = threadIdx.x, lane = tid & 63, wv = tid >> 6;
  __shared__ int wsum[4];
  __shared__ int cbase;
  if (tid == 0) {
    int b = 0;
    for (int i = 0; i < e; ++i) b += counts[i];
    cbase = b;
  }
  __syncthreads();
  for (int c0 = 0; c0 < TOK; c0 += 256) {
    const int t = c0 + tid;
    const int a = topi[2 * t], b = topi[2 * t + 1];
    const int k = (a == e) ? 0 : ((b == e) ? 1 : -1);
    const unsigned long long bal = __ballot(k >= 0);
    const int rank = __popcll(bal & ((1ull << lane) - 1ull));
    if (lane == 0) wsum[wv] = __popcll(bal);
    __syncthreads();
    int woff = 0;
#pragma unroll
    for (int i = 0; i < 4; ++i) if (i < wv) woff += wsum[i];
    const int ctot = wsum[0] + wsum[1] + wsum[2] + wsum[3];
    if (k >= 0) {
      const int pos = cbase + woff + rank;
      perm[pos] = t;
      prow[pos] = topp[2 * t + k];
    }
    __syncthreads();
    if (tid == 0) cbase += ctot;
    __syncthreads();
  }
}

// ---- inline tile decode (BM=128): tix -> (e, m0, off, ne); false if dead ----
static __device__ __forceinline__ bool decode128(const int* counts, int tix,
                                                 int& e, int& m0, int& off, int& ne) {
  int t = tix; off = 0;
  for (e = 0; e < NE; ++e) {
    const int c = counts[e];
    const int nt = (c + 127) >> 7;
    if (t < nt) { m0 = t << 7; ne = c; return true; }
    t -= nt; off += c;
  }
  return false;
}

// ---------------- GEMM1 (+ w3-transpose tail blocks) ----------------
// blocks [0, G1TILES): X(gathered bf16) @ wgu -> h = silu(g)*u
//   BM=128, BN=128 wgu-rows (64 h-cols), BK=64; 4 waves; depth-2 counted-vmcnt dbuf.
// blocks [G1TILES, G1TILES+4096): w3 [H][D] fp32 -> w3t [D][H] bf16 (64x64 tiles).
//   These fill CUs as gemm1 tiles retire; w3t consumed only by gemm2 (next dispatch).
__global__ __launch_bounds__(256) void gemm1_k(
    const unsigned short* __restrict__ Xb, const unsigned short* __restrict__ wgu,
    const int* __restrict__ counts, const int* __restrict__ perm,
    unsigned short* __restrict__ hbuf,
    const float* __restrict__ w3, unsigned short* __restrict__ w3t) {
  __shared__ unsigned short As[2][128 * 64];
  __shared__ unsigned short Bs[2][128 * 64];

  const int tid = threadIdx.x, lane = tid & 63, wv = tid >> 6;

  if (blockIdx.x >= G1TILES) {
    // ---- w3 transpose tail ----
    unsigned short* tbuf = &As[0][0];   // 9216B of the 16KB buffer
    const int bid = blockIdx.x - G1TILES;
    const int e = bid >> 9, xt = bid & 511;
    const int tc = xt & 15, tr = xt >> 4;
    const int c0 = tc * 64, r0 = tr * 64;
    const float* in = w3 + (size_t)e * HH * DD;
#pragma unroll
    for (int p = 0; p < 4; ++p) {
      const int rb = (wv * 4 + p) * 4;
      ushort4 o;
      o.x = f2bf(in[(size_t)(r0 + rb + 0) * DD + c0 + lane]);
      o.y = f2bf(in[(size_t)(r0 + rb + 1) * DD + c0 + lane]);
      o.z = f2bf(in[(size_t)(r0 + rb + 2) * DD + c0 + lane]);
      o.w = f2bf(in[(size_t)(r0 + rb + 3) * DD + c0 + lane]);
      *(ushort4*)&tbuf[lane * 72 + rb] = o;
    }
    __syncthreads();
#pragma unroll
    for (int q = 0; q < 2; ++q) {
      const int idx = q * 256 + tid;
      const int crow = idx >> 3, seg = idx & 7;
      *(uint4*)&w3t[((size_t)e * DD + c0 + crow) * HH + r0 + seg * 8] =
          *(const uint4*)&tbuf[crow * 72 + seg * 8];
    }
    return;
  }

  const int bx = blockIdx.x & 31;
  int e, m0, off, ne;
  if (!decode128(counts, blockIdx.x >> 5, e, m0, off, ne)) return;

  const int srow = lane >> 3;
  const int schunk = ((lane & 7) ^ srow) * 8;

  const unsigned short* pA[4];
  const unsigned short* pB[4];
#pragma unroll
  for (int q = 0; q < 4; ++q) {
    const int row = wv * 32 + q * 8 + srow;
    pA[q] = Xb + (size_t)perm[off + min(m0 + row, ne - 1)] * DD + schunk;
    pB[q] = wgu + ((size_t)e * 2 * HH + bx * 128 + row) * DD + schunk;
  }

  const int wr = wv >> 1, wc = wv & 1;
  const int lr = lane & 15, kc = lane >> 4;

  f32x4 acc[4][4];
#pragma unroll
  for (int a = 0; a < 4; ++a)
#pragma unroll
    for (int b = 0; b < 4; ++b) acc[a][b] = f32x4{0.f, 0.f, 0.f, 0.f};

#define G1_ISSUE(b)                                                       \
  do {                                                                    \
    _Pragma("unroll")                                                     \
    for (int q = 0; q < 4; ++q) {                                         \
      gload16(pA[q], &As[b][(wv * 32 + q * 8) * 64]); pA[q] += 64;        \
      gload16(pB[q], &Bs[b][(wv * 32 + q * 8) * 64]); pB[q] += 64;        \
    }                                                                     \
  } while (0)

#define G1_COMPUTE(b)                                                     \
  do {                                                                    \
    _Pragma("unroll")                                                     \
    for (int kk = 0; kk < 2; ++kk) {                                      \
      bf16x8 af[4], bf[4];                                                \
      _Pragma("unroll")                                                   \
      for (int mf = 0; mf < 4; ++mf)                                      \
        af[mf] = *(const bf16x8*)&As[b][(wr * 64 + mf * 16 + lr) * 64 +   \
                                       ((kk * 4 + kc) ^ (lr & 7)) * 8];   \
      _Pragma("unroll")                                                   \
      for (int nf = 0; nf < 4; ++nf)                                      \
        bf[nf] = *(const bf16x8*)&Bs[b][(wc * 64 + nf * 16 + lr) * 64 +   \
                                       ((kk * 4 + kc) ^ (lr & 7)) * 8];   \
      _Pragma("unroll")                                                   \
      for (int mf = 0; mf < 4; ++mf)                                      \
        _Pragma("unroll")                                                 \
        for (int nf = 0; nf < 4; ++nf)                                    \
          acc[mf][nf] = __builtin_amdgcn_mfma_f32_16x16x32_bf16(          \
              af[mf], bf[nf], acc[mf][nf], 0, 0, 0);                      \
    }                                                                     \
  } while (0)

  G1_ISSUE(0);
  G1_ISSUE(1);
  VMCNT8(); BARX();
  for (int t = 0; t < DD / 64; ++t) {
    const int cur = t & 1;
    G1_COMPUTE(cur);
    if (t == DD / 64 - 1) break;
    BARX();                                  // all waves done reading buf[cur]
    if (t < DD / 64 - 2) { G1_ISSUE(cur); VMCNT8(); }   // tile t+2 in; wait t+1
    else VMCNT0();
    BARX();                                  // tile t+1 visible
  }

  // epilogue: nf even = G, nf odd = U (same 16 h-cols)
#pragma unroll
  for (int mf = 0; mf < 4; ++mf)
#pragma unroll
    for (int np = 0; np < 2; ++np) {
      const f32x4 g = acc[mf][2 * np], u = acc[mf][2 * np + 1];
      const int hcol = bx * 64 + (wc * 2 + np) * 16 + lr;
#pragma unroll
      for (int r = 0; r < 4; ++r) {
        const int rl = m0 + wr * 64 + mf * 16 + kc * 4 + r;
        if (rl < ne) {
          const float gg = g[r], uu = u[r];
          const float hv = gg / (1.f + __expf(-gg)) * uu;
          hbuf[(size_t)(off + rl) * HH + hcol] = f2bf(hv);
        }
      }
    }
#undef G1_ISSUE
#undef G1_COMPUTE
}

// ---------------- GEMM2: h(bf16) @ w3t(bf16) * prob -> atomicAdd into out ----------------
// BM=128, BN=128, BK=64; 4 waves (2x2); depth-2 counted-vmcnt dbuf; K=2048.
__global__ __launch_bounds__(256) void gemm2_k(
    const unsigned short* __restrict__ hbuf, const unsigned short* __restrict__ w3t,
    const int* __restrict__ counts, const int* __restrict__ perm,
    const float* __restrict__ prow, float* __restrict__ out) {
  const int bx = blockIdx.x & 7;
  int e, m0, off, ne;
  if (!decode128(counts, blockIdx.x >> 3, e, m0, off, ne)) return;
  const int n1 = bx * 128;

  __shared__ unsigned short As[2][128 * 64];
  __shared__ unsigned short Bs[2][128 * 64];

  const int tid = threadIdx.x, lane = tid & 63, wv = tid >> 6;
  const int srow = lane >> 3;
  const int schunk = ((lane & 7) ^ srow) * 8;

  const unsigned short* pA[4];
  const unsigned short* pB[4];
#pragma unroll
  for (int q = 0; q < 4; ++q) {
    const int row = wv * 32 + q * 8 + srow;
    pA[q] = hbuf + (size_t)(off + min(m0 + row, ne - 1)) * HH + schunk;
    pB[q] = w3t + ((size_t)e * DD + n1 + row) * HH + schunk;
  }

  const int wr = wv >> 1, wc = wv & 1;
  const int lr = lane & 15, kc = lane >> 4;

  f32x4 acc[4][4];
#pragma unroll
  for (int a = 0; a < 4; ++a)
#pragma unroll
    for (int b = 0; b < 4; ++b) acc[a][b] = f32x4{0.f, 0.f, 0.f, 0.f};

#define G2_ISSUE(b)                                                       \
  do {                                                                    \
    _Pragma("unroll")                                                     \
    for (int q = 0; q < 4; ++q) {                                         \
      gload16(pA[q], &As[b][(wv * 32 + q * 8) * 64]); pA[q] += 64;        \
      gload16(pB[q], &Bs[b][(wv * 32 + q * 8) * 64]); pB[q] += 64;        \
    }                                                                     \
  } while (0)

#define G2_COMPUTE(b)                                                     \
  do {                                                                    \
    _Pragma("unroll")                                                     \
    for (int kk = 0; kk < 2; ++kk) {                                      \
      bf16x8 af[4], bf[4];                                                \
      _Pragma("unroll")                                                   \
      for (int mf = 0; mf < 4; ++mf)                                      \
        af[mf] = *(const bf16x8*)&As[b][(wr * 64 + mf * 16 + lr) * 64 +   \
                                       ((kk * 4 + kc) ^ (lr & 7)) * 8];   \
      _Pragma("unroll")                                                   \
      for (int nf = 0; nf < 4; ++nf)                                      \
        bf[nf] = *(const bf16x8*)&Bs[b][(wc * 64 + nf * 16 + lr) * 64 +   \
                                       ((kk * 4 + kc) ^ (lr & 7)) * 8];   \
      _Pragma("unroll")                                                   \
      for (int mf = 0; mf < 4; ++mf)                                      \
        _Pragma("unroll")                                                 \
        for (int nf = 0; nf < 4; ++nf)                                    \
          acc[mf][nf] = __builtin_amdgcn_mfma_f32_16x16x32_bf16(          \
              af[mf], bf[nf], acc[mf][nf], 0, 0, 0);                      \
    }                                                                     \
  } while (0)

  G2_ISSUE(0);
  G2_ISSUE(1);
  VMCNT8(); BARX();
  for (int t = 0; t < HH / 64; ++t) {
    const int cur = t & 1;
    G2_COMPUTE(cur);
    if (t == HH / 64 - 1) break;
    BARX();
    if (t < HH / 64 - 2) { G2_ISSUE(cur); VMCNT8(); }
    else VMCNT0();
    BARX();
  }

  // epilogue: out[tok] += prob * acc  (fp32 atomic add, commutative -> deterministic)
#pragma unroll
  for (int mf = 0; mf < 4; ++mf)
#pragma unroll
    for (int r = 0; r < 4; ++r) {
      const int rl = m0 + wr * 64 + mf * 16 + kc * 4 + r;
      if (rl < ne) {
        const int tok = perm[off + rl];
        const float p = prow[off + rl];
        float* op = out + (size_t)tok * DD + n1 + wc * 64 + lr;
#pragma unroll
        for (int nf = 0; nf < 4; ++nf)
          atomicAdd(op + nf * 16, p * acc[mf][nf][r]);
      }
    }
#undef G2_ISSUE
#undef G2_COMPUTE
}

// ---------------- workspace layout ----------------
#define WS_COUNTS 0
#define WS_TOPI 128
#define WS_TOPP (WS_TOPI + TOK * 2 * 4)
#define WS_PERM (WS_TOPP + TOK * 2 * 4)
#define WS_PROW (WS_PERM + RTOT * 4)
#define WS_XB ((WS_PROW + RTOT * 4 + 255) & ~(size_t)255)
#define WS_H (WS_XB + (size_t)TOK * DD * 2)
#define WS_WGU (WS_H + (size_t)RTOT * HH * 2)
#define WS_W3T (WS_WGU + (size_t)NE * 2 * HH * DD * 2)
// end = WS_W3T + NE*DD*HH*2 ~= 136 MB

extern "C" void kernel_launch(void* const* d_in, const int* in_sizes, int n_in,
                              void* d_out, int out_size, void* d_ws, size_t ws_size,
                              hipStream_t stream) {
  const float* x = (const float*)d_in[0];
  const float* gw = (const float*)d_in[1];
  const float* w1 = (const float*)d_in[2];
  const float* w2 = (const float*)d_in[3];
  const float* w3 = (const float*)d_in[4];
  float* out = (float*)d_out;
  char* ws = (char*)d_ws;

  int* counts = (int*)(ws + WS_COUNTS);
  int* topi = (int*)(ws + WS_TOPI);
  float* topp = (float*)(ws + WS_TOPP);
  int* perm = (int*)(ws + WS_PERM);
  float* prow = (float*)(ws + WS_PROW);
  unsigned short* Xb = (unsigned short*)(ws + WS_XB);
  unsigned short* hbuf = (unsigned short*)(ws + WS_H);
  unsigned short* wgu = (unsigned short*)(ws + WS_WGU);
  unsigned short* w3t = (unsigned short*)(ws + WS_W3T);

  hipMemsetAsync(ws, 0, 128, stream);
  hipMemsetAsync(out, 0, (size_t)out_size * sizeof(float), stream);
  // router (1024) + w1/w2 transpose (8192)
  pre_k<<<1024 + 8192, 256, 0, stream>>>(x, gw, Xb, topi, topp, counts, w1, w2, wgu);
  compact_k<<<NE, 256, 0, stream>>>(topi, topp, counts, perm, prow);
  // gemm1 tiles (2304) + w3-transpose tail (4096) in ONE dispatch: transpose hides
  // under gemm1 compute; w3t is consumed only by the next dispatch (gemm2).
  gemm1_k<<<G1TILES + 4096, 256, 0, stream>>>(Xb, wgu, counts, perm, hbuf, w3, w3t);
  gemm2_k<<<MAXT1 * 8, 256, 0, stream>>>(hbuf, w3t, counts, perm, prow, out);
}